// Round 17
// baseline (226.904 us; speedup 1.0000x reference)
//
#include <hip/hip_runtime.h>
#include <type_traits>

typedef __bf16 bf16_t;
typedef __attribute__((ext_vector_type(8))) __bf16 bf16x8;
typedef __attribute__((ext_vector_type(4))) float f32x4;
typedef __attribute__((ext_vector_type(16))) float f32x16;

__device__ __forceinline__ void async16(const void* g, void* lds) {
  __builtin_amdgcn_global_load_lds((const __attribute__((address_space(1))) unsigned int*)g,
                                   (__attribute__((address_space(3))) unsigned int*)lds, 16, 0, 0);
}

__device__ __forceinline__ unsigned pk2(float lo, float hi) {
  unsigned short a = __builtin_bit_cast(unsigned short, (__bf16)lo);
  unsigned short b = __builtin_bit_cast(unsigned short, (__bf16)hi);
  return (unsigned)a | ((unsigned)b << 16);
}

// exchange register halves across lane<32 / lane>=32 (VALU pipe, not LDS)
__device__ __forceinline__ void plswap(unsigned& a, unsigned& b) {
#if __has_builtin(__builtin_amdgcn_permlane32_swap)
  auto r = __builtin_amdgcn_permlane32_swap((int)a, (int)b, false, false);
  a = (unsigned)r[0];
  b = (unsigned)r[1];
#else
  const bool hb = (threadIdx.x & 32) != 0;
  unsigned bx = (unsigned)__shfl_xor((int)b, 32);
  unsigned ax = (unsigned)__shfl_xor((int)a, 32);
  unsigned na = hb ? bx : a;
  unsigned nb = hb ? b : ax;
  a = na; b = nb;
#endif
}

// ---------------- merged prep: pack_mask | wt transpose-cvt | from-cvt | to-cvt ----------------
__global__ __launch_bounds__(256) void prep_kernel(const int* __restrict__ mask, unsigned long long* __restrict__ mb,
                                                   const float* __restrict__ Wq, const float* __restrict__ Wk,
                                                   const float* __restrict__ Wv, bf16_t* __restrict__ Wt,
                                                   const float* __restrict__ from, bf16_t* __restrict__ inbF,
                                                   const float* __restrict__ to_, bf16_t* __restrict__ inbT) {
  const int bid = blockIdx.x, tid = threadIdx.x;
  if (bid < 2048) {
    const int lane = tid & 63, w = tid >> 6;
    for (int i = 0; i < 32; ++i) {
      size_t word = (size_t)bid * 128 + (size_t)i * 4 + w;
      unsigned long long bits = __ballot(mask[word * 64 + lane] != 0);
      if (lane == 0) mb[word] = bits;
    }
  } else if (bid < 3584) {
    const int idx = bid - 2048;
    const int z = idx >> 9, r = idx & 511;
    const float* src = (z == 0) ? Wq : ((z == 1) ? Wk : Wv);
    const float sc = (z == 0) ? 0.18033688011112042f : 1.0f;  // (1/8)*log2(e)
    bf16_t* dst = Wt + (size_t)z * 1024 * 1024;
    const int n = (r & 15) * 64 + (tid & 63);
    const int k8 = (r >> 4) * 4 + (tid >> 6);
    bf16x8 o;
#pragma unroll
    for (int j = 0; j < 8; ++j) o[j] = (__bf16)(src[(size_t)(k8 * 8 + j) * 1024 + n] * sc);
    *(bf16x8*)(dst + (size_t)n * 1024 + k8 * 8) = o;
  } else {
    const bool isF = bid < 7680;
    const size_t i = (size_t)(bid - (isF ? 3584 : 7680)) * 256 + tid;
    const float4* in4 = (const float4*)(isF ? from : to_);
    bf16_t* outp = isF ? inbF : inbT;
    float4 a = in4[i * 2], b = in4[i * 2 + 1];
    bf16x8 o;
    o[0] = (__bf16)a.x; o[1] = (__bf16)a.y; o[2] = (__bf16)a.z; o[3] = (__bf16)a.w;
    o[4] = (__bf16)b.x; o[5] = (__bf16)b.y; o[6] = (__bf16)b.z; o[7] = (__bf16)b.w;
    *(bf16x8*)(outp + i * 8) = o;
  }
}

// ---------------- merged projection GEMM (double-buffered BK=32), z = blockIdx.z ----------------
__global__ __launch_bounds__(256) void proj_kernel(const bf16_t* __restrict__ inbF, const bf16_t* __restrict__ inbT,
                                                   const bf16_t* __restrict__ Wt,
                                                   const float* __restrict__ bq, const float* __restrict__ bk,
                                                   const float* __restrict__ bv,
                                                   bf16_t* __restrict__ Qw, bf16_t* __restrict__ Kw,
                                                   bf16_t* __restrict__ Vw) {
  __shared__ __align__(16) unsigned char smem[33792];
  bf16_t* se = (bf16_t*)smem;
  const int z = blockIdx.z;
  const bf16_t* A = (z == 0) ? inbF : inbT;
  const bf16_t* Wz = Wt + (size_t)z * 1024 * 1024;
  const float* bias = (z == 0) ? bq : ((z == 1) ? bk : bv);
  bf16_t* dst = (z == 0) ? Qw : ((z == 1) ? Kw : Vw);
  const float bscale = (z == 0) ? 0.18033688011112042f : 1.0f;

  const int tid = threadIdx.x, lane = tid & 63, w = tid >> 6;
  const int m0 = blockIdx.x * 128, n0 = blockIdx.y * 128;
  const int wm = (w >> 1) * 64, wn = (w & 1) * 64;
  const int r = lane & 15, kq = lane >> 4;
  const int srow = lane >> 2, sslot = lane & 3;
  f32x4 acc[4][4] = {};

  auto stage = [&](int buf, int k0) {
    bf16_t* Ad = se + buf * 4096;
    bf16_t* Bd = se + 8192 + buf * 4096;
#pragma unroll
    for (int it = 0; it < 2; ++it) {
      const int c = it * 4 + w;
      const int row = c * 16 + srow;
      async16(A + (size_t)(m0 + row) * 1024 + k0 + ((sslot ^ (row & 3)) * 8), Ad + c * 512);
      async16(Wz + (size_t)(n0 + row) * 1024 + k0 + ((sslot ^ (row & 3)) * 8), Bd + c * 512);
    }
  };

  stage(0, 0);
  __syncthreads();
  for (int tile = 0; tile < 32; ++tile) {
    const int cur = tile & 1;
    if (tile < 31) stage(cur ^ 1, (tile + 1) * 32);
    const bf16_t* Al = se + cur * 4096;
    const bf16_t* Bl = se + 8192 + cur * 4096;
    bf16x8 af[4], bfr[4];
#pragma unroll
    for (int i = 0; i < 4; ++i) {
      const int ra = wm + i * 16 + r;
      af[i] = *(const bf16x8*)(Al + ra * 32 + ((kq ^ (ra & 3)) * 8));
      const int rb = wn + i * 16 + r;
      bfr[i] = *(const bf16x8*)(Bl + rb * 32 + ((kq ^ (rb & 3)) * 8));
    }
    __builtin_amdgcn_s_setprio(1);
#pragma unroll
    for (int i = 0; i < 4; ++i)
#pragma unroll
      for (int j = 0; j < 4; ++j)
        acc[i][j] = __builtin_amdgcn_mfma_f32_16x16x32_bf16(af[i], bfr[j], acc[i][j], 0, 0, 0);
    __builtin_amdgcn_s_setprio(0);
    __syncthreads();
  }

  bf16_t* Cl = se;
  float bvv[4];
#pragma unroll
  for (int j = 0; j < 4; ++j) bvv[j] = bias[n0 + wn + j * 16 + r] * bscale;
#pragma unroll
  for (int i = 0; i < 4; ++i)
#pragma unroll
    for (int j = 0; j < 4; ++j)
#pragma unroll
      for (int g = 0; g < 4; ++g)
        Cl[(wm + i * 16 + kq * 4 + g) * 132 + wn + j * 16 + r] = (__bf16)(acc[i][j][g] + bvv[j]);
  __syncthreads();

  const int b = m0 >> 11, sbase = m0 & 2047;
  if (z == 0) {
#pragma unroll
    for (int q = 0; q < 8; ++q) {
      const int cid = q * 256 + tid;
      const int m = cid >> 4, c = (cid >> 3) & 1, d8 = cid & 7;
      bf16x8 val = *(const bf16x8*)(Cl + m * 132 + c * 64 + d8 * 8);
      *(bf16x8*)(dst + ((size_t)(b * 16 + (n0 >> 6) + c) * 2048 + sbase + m) * 64 + d8 * 8) = val;
    }
  } else if (z == 1) {
#pragma unroll
    for (int q = 0; q < 8; ++q) {
      const int cid = q * 256 + tid;
      const int hh = cid >> 7, m = cid & 127;
      bf16x8 val;
#pragma unroll
      for (int dd = 0; dd < 8; ++dd) val[dd] = Cl[m * 132 + dd * 16 + hh];
      *(bf16x8*)(dst + ((size_t)(b * 16 + hh) * 2048 + sbase + m) * 64 + (n0 >> 4)) = val;
    }
  } else {
#pragma unroll
    for (int q = 0; q < 8; ++q) {
      const int cid = q * 256 + tid;
      const int nl = cid >> 4, m8 = cid & 15;
      bf16x8 val;
#pragma unroll
      for (int s = 0; s < 8; ++s) val[s] = Cl[(m8 * 8 + s) * 132 + nl];
      const int hh = (n0 >> 6) + (nl >> 6), dd = nl & 63;
      *(bf16x8*)(dst + ((size_t)(b * 16 + hh) * 64 + dd) * 2048 + sbase + m8 * 8) = val;
    }
  }
}

// ---------------- flash attention, split-T: each block does 16 of 32 t-tiles ----------------
// grid 1024 blocks = 4/CU -> 4 waves/SIMD (VGPR 128x4=512/SIMD exact; LDS 4x32KB=128<=160).
// Same inner loop as the proven 115us kernel; per-wave work/fragment reuse UNCHANGED (the R7
// confound removed). Fixed-max softmax => halves combine linearly: out=(O0+O1)/(l0+l1).
// half0 partials -> d_out (final layout, divide deferred); half1 -> ws; row-sums l -> Lp.
__global__ __launch_bounds__(256, 2) void attn_part_kernel(const bf16_t* __restrict__ Q, const bf16_t* __restrict__ K,
                                                           const bf16_t* __restrict__ VT,
                                                           const unsigned long long* __restrict__ mb,
                                                           float* __restrict__ Op0, float* __restrict__ Op1,
                                                           float* __restrict__ Lp) {
  __shared__ __align__(16) unsigned char smem[32768];  // K0 K1 V0 V1 (8KB each)
  bf16_t* se = (bf16_t*)smem;
  const int tid = threadIdx.x, lane = tid & 63, w = tid >> 6;
  const int cl = lane & 31, hi = lane >> 5;

  // XCD-locality remap: lid&7 = XCD; each XCD serves 8 whole (b,h) pairs (16 blocks each).
  const int lid = blockIdx.x;
  const int xcd = lid & 7, q_ = lid >> 3;
  const int pairIdx = xcd * 8 + (q_ & 7);
  const int rest = q_ >> 3;               // 0..15
  const int f0 = (rest & 7) * 256;
  const int half = rest >> 3;             // 0 or 1
  const int tbase = half * 16;
  const int h = pairIdx & 15, b = pairIdx >> 4;

  const size_t bh = (size_t)b * 16 + h;
  const int fw = f0 + w * 64;
  float* Ob = half ? Op1 : Op0;

  // Q B-frags: qf[fb][ks] = Q[fw + fb*32 + cl][ks*16 + hi*8 + j]
  const bf16_t* Qb = Q + (bh * 2048 + fw) * 64;
  bf16x8 qf[2][4];
#pragma unroll
  for (int fb = 0; fb < 2; ++fb)
#pragma unroll
    for (int ks = 0; ks < 4; ++ks)
      qf[fb][ks] = *(const bf16x8*)(Qb + (fb * 32 + cl) * 64 + ks * 16 + hi * 8);

  f32x16 Of[2][2] = {};     // [fb][db]: O[row=f][col=d], col = db*32+cl
  float lacc[2] = {0.f, 0.f};
  bf16x8 paw[2][4];         // [fb][kt] PV A-frags from prev tile's softmax

  const unsigned long long* mrow[2];
  mrow[0] = mb + ((size_t)b * 2048 + fw + cl) * 32 + tbase;
  mrow[1] = mb + ((size_t)b * 2048 + fw + 32 + cl) * 32 + tbase;

  // hoisted per-thread staging bases (pre-swizzled global source, linear LDS dest)
  const int row8 = lane >> 3, slot = lane & 7;
  const int swz = (slot ^ row8) * 8;
  const bf16_t* kgb[2];
  const bf16_t* vgb[2];
#pragma unroll
  for (int it = 0; it < 2; ++it) {
    const int row = it * 32 + w * 8 + row8;
    kgb[it] = K + (bh * 2048 + (size_t)tbase * 64 + row) * 64 + swz;
    vgb[it] = VT + (bh * 64 + row) * 2048 + (size_t)tbase * 64 + swz;
  }

  auto stage_k = [&](int buf, int tile) {
    bf16_t* kd = se + buf * 4096 + w * 512;
#pragma unroll
    for (int it = 0; it < 2; ++it)
      async16(kgb[it] + (size_t)tile * 4096, kd + it * 2048);
  };
  auto stage_v = [&](int buf, int tile) {
    bf16_t* vd = se + 8192 + buf * 4096 + w * 512;
#pragma unroll
    for (int it = 0; it < 2; ++it)
      async16(vgb[it] + (size_t)tile * 64, vd + it * 2048);
  };

  auto pv_step = [&](int vbuf) {
    const bf16_t* Vl = se + 8192 + vbuf * 4096;
    __builtin_amdgcn_s_setprio(1);
#pragma unroll
    for (int db = 0; db < 2; ++db) {
      const int vrow0 = db * 32 + cl;
#pragma unroll
      for (int kt = 0; kt < 4; ++kt) {
        bf16x8 vf = *(const bf16x8*)(Vl + vrow0 * 64 + (((2 * kt + hi) ^ (vrow0 & 7)) * 8));
        Of[0][db] = __builtin_amdgcn_mfma_f32_32x32x16_bf16(paw[0][kt], vf, Of[0][db], 0, 0, 0);
        Of[1][db] = __builtin_amdgcn_mfma_f32_32x32x16_bf16(paw[1][kt], vf, Of[1][db], 0, 0, 0);
      }
    }
    __builtin_amdgcn_s_setprio(0);
  };

  unsigned long long mA[2], mB[2];
  stage_k(0, 0);
  mA[0] = mrow[0][0];
  mA[1] = mrow[1][0];
  __syncthreads();

  auto body = [&](auto curc, auto dopvc, unsigned long long (&mc)[2], unsigned long long (&mn)[2], int tile) {
    constexpr int cur = decltype(curc)::value;
    constexpr bool dopv = decltype(dopvc)::value;
    if (tile < 15) {
      stage_k(cur ^ 1, tile + 1);
      mn[0] = mrow[0][tile + 1];
      mn[1] = mrow[1][tile + 1];
    }
    stage_v(cur, tile);
    const bf16_t* Kl = se + cur * 4096;

    // C-init from mask bits: st = bit ? 0 : -30000
    f32x16 st0[2], st1[2];
#pragma unroll
    for (int fb = 0; fb < 2; ++fb) {
      const unsigned mw0 = (unsigned)(mc[fb] >> (4 * hi));
      const unsigned mw1 = (unsigned)(mc[fb] >> (32 + 4 * hi));
#pragma unroll
      for (int q = 0; q < 4; ++q)
#pragma unroll
        for (int e = 0; e < 4; ++e) {
          const int idx = q * 4 + e;
          const int pos = e + 8 * q;
          const unsigned s0 = (unsigned)(((int)(mw0 << (31 - pos))) >> 31);
          const unsigned s1 = (unsigned)(((int)(mw1 << (31 - pos))) >> 31);
          st0[fb][idx] = __uint_as_float(~s0 & 0xC6EA6000u);
          st1[fb][idx] = __uint_as_float(~s1 & 0xC6EA6000u);
        }
    }

    // QK ts=0
    {
      const int krow = cl;
      __builtin_amdgcn_s_setprio(1);
#pragma unroll
      for (int ks = 0; ks < 4; ++ks) {
        bf16x8 kf = *(const bf16x8*)(Kl + krow * 64 + (((2 * ks + hi) ^ (krow & 7)) * 8));
        st0[0] = __builtin_amdgcn_mfma_f32_32x32x16_bf16(kf, qf[0][ks], st0[0], 0, 0, 0);
        st0[1] = __builtin_amdgcn_mfma_f32_32x32x16_bf16(kf, qf[1][ks], st0[1], 0, 0, 0);
      }
      __builtin_amdgcn_s_setprio(0);
    }

    if constexpr (dopv) pv_step(cur ^ 1);

    // QK ts=1
    {
      const int krow = 32 + cl;
      __builtin_amdgcn_s_setprio(1);
#pragma unroll
      for (int ks = 0; ks < 4; ++ks) {
        bf16x8 kf = *(const bf16x8*)(Kl + krow * 64 + (((2 * ks + hi) ^ (krow & 7)) * 8));
        st1[0] = __builtin_amdgcn_mfma_f32_32x32x16_bf16(kf, qf[0][ks], st1[0], 0, 0, 0);
        st1[1] = __builtin_amdgcn_mfma_f32_32x32x16_bf16(kf, qf[1][ks], st1[1], 0, 0, 0);
      }
      __builtin_amdgcn_s_setprio(0);
    }

    // softmax: p = exp2(st) (masked underflow to 0) -> lacc -> pack -> swap -> paw
#pragma unroll
    for (int ts = 0; ts < 2; ++ts) {
#pragma unroll
      for (int fb = 0; fb < 2; ++fb) {
        const f32x16& stf = (ts == 0) ? st0[fb] : st1[fb];
        float pv[16];
#pragma unroll
        for (int q = 0; q < 4; ++q)
#pragma unroll
          for (int e = 0; e < 4; ++e) {
            const int idx = q * 4 + e;
            float p = __builtin_amdgcn_exp2f(stf[idx]);
            lacc[fb] += p;
            pv[idx] = p;
          }
#pragma unroll
        for (int kl = 0; kl < 2; ++kl) {
          const int qa = 2 * kl, qb = qa + 1;
          unsigned x0 = pk2(pv[qa * 4 + 0], pv[qa * 4 + 1]);
          unsigned y0 = pk2(pv[qb * 4 + 0], pv[qb * 4 + 1]);
          unsigned x1 = pk2(pv[qa * 4 + 2], pv[qa * 4 + 3]);
          unsigned y1 = pk2(pv[qb * 4 + 2], pv[qb * 4 + 3]);
          plswap(x0, y0);
          plswap(x1, y1);
          union { unsigned u[4]; bf16x8 v; } tmp;
          tmp.u[0] = x0; tmp.u[1] = x1; tmp.u[2] = y0; tmp.u[3] = y1;
          paw[fb][ts * 2 + kl] = tmp.v;
        }
      }
    }
    __syncthreads();
  };

  using c0 = std::integral_constant<int, 0>;
  using c1 = std::integral_constant<int, 1>;
  using bF = std::integral_constant<bool, false>;
  using bT = std::integral_constant<bool, true>;

  body(c0{}, bF{}, mA, mB, 0);
  body(c1{}, bT{}, mB, mA, 1);
  for (int tile = 2; tile < 16; tile += 2) {
    body(c0{}, bT{}, mA, mB, tile);
    body(c1{}, bT{}, mB, mA, tile + 1);
  }
  pv_step(1);  // PV of tile 15 (Vbuf[15&1]=1)

  // ---- epilogue: store raw partials (no divide). l rows: lane cl holds f=fw+fb*32+cl after swap
#pragma unroll
  for (int fb = 0; fb < 2; ++fb) lacc[fb] += __shfl_xor(lacc[fb], 32);
  if (hi == 0) {
#pragma unroll
    for (int fb = 0; fb < 2; ++fb)
      Lp[(size_t)half * 131072 + bh * 2048 + fw + fb * 32 + cl] = lacc[fb];
  }
#pragma unroll
  for (int fb = 0; fb < 2; ++fb)
#pragma unroll
    for (int q = 0; q < 4; ++q)
#pragma unroll
      for (int e = 0; e < 4; ++e) {
        const int idx = q * 4 + e;
        const int row = e + 8 * q + 4 * hi;
        const size_t orow = ((size_t)b * 2048 + fw + fb * 32 + row) * 1024 + h * 64;
        Ob[orow + cl] = Of[fb][0][idx];
        Ob[orow + 32 + cl] = Of[fb][1][idx];
      }
}

// ---------------- combine halves: out = (O0 + O1) / (l0 + l1), in place over O0 (= d_out) ----------------
__global__ __launch_bounds__(256) void attn_reduce_kernel(float* __restrict__ Op0, const float* __restrict__ Op1,
                                                          const float* __restrict__ Lp) {
  const size_t i4 = ((size_t)blockIdx.x * 256 + threadIdx.x) * 4;
  const size_t rowd = i4 >> 6;                 // [b][f][h] linear
  const int hh = (int)(rowd & 15);
  const size_t bf = rowd >> 4;                 // b*2048+f
  const int bb = (int)(bf >> 11);
  const size_t lidx = ((size_t)bb * 16 + hh) * 2048 + (bf & 2047);
  const float li = 1.0f / (Lp[lidx] + Lp[131072 + lidx]);
  f32x4 a = *(const f32x4*)(Op0 + i4);
  f32x4 c = *(const f32x4*)(Op1 + i4);
  *(f32x4*)(Op0 + i4) = (a + c) * li;
}

extern "C" void kernel_launch(void* const* d_in, const int* in_sizes, int n_in,
                              void* d_out, int out_size, void* d_ws, size_t ws_size,
                              hipStream_t stream) {
  (void)in_sizes; (void)n_in; (void)out_size; (void)ws_size;
  const float* from = (const float*)d_in[0];
  const float* to_  = (const float*)d_in[1];
  const int*   mask = (const int*)d_in[2];
  const float* Wq = (const float*)d_in[3];
  const float* bq = (const float*)d_in[4];
  const float* Wk = (const float*)d_in[5];
  const float* bk = (const float*)d_in[6];
  const float* Wv = (const float*)d_in[7];
  const float* bv = (const float*)d_in[8];
  float* out = (float*)d_out;
  char* ws = (char*)d_ws;

  bf16_t* Qw = (bf16_t*)(ws);                                    // 16 MiB [B,H,F,D]
  bf16_t* Kw = (bf16_t*)(ws + (size_t)(1u << 24));               // 16 MiB [B,H,T,D]
  bf16_t* Vw = (bf16_t*)(ws + (size_t)(2u << 24));               // 16 MiB [B,H,D,T]
  bf16_t* Wt = (bf16_t*)(ws + (size_t)(3u << 24));               // 6 MiB (3x [1024][1024])
  unsigned long long* mbits = (unsigned long long*)(ws + (size_t)(3u << 24) + (size_t)(6u << 20));  // 2 MiB
  float* Op1 = (float*)(ws + (size_t)(3u << 24) + (size_t)(8u << 20));   // 32 MiB O-partial half1
  float* Lp  = (float*)(ws + (size_t)(3u << 24) + (size_t)(8u << 20) + ((size_t)1 << 25));  // 1 MiB l rows
  // bf16 input scratch lives in d_out (dead once proj completes; attn partials overwrite after)
  bf16_t* inbT = (bf16_t*)d_out;                       // to-tensor bf16 (16 MiB)
  bf16_t* inbF = (bf16_t*)((char*)d_out + (1u << 24)); // from-tensor bf16 (16 MiB)
  float* Op0 = out;                                    // O-partial half0 = final out (in-place)

  prep_kernel<<<11776, 256, 0, stream>>>(mask, mbits, Wq, Wk, Wv, Wt, from, inbF, to_, inbT);
  proj_kernel<<<dim3(64, 8, 3), 256, 0, stream>>>(inbF, inbT, Wt, bq, bk, bv, Qw, Kw, Vw);
  attn_part_kernel<<<1024, 256, 0, stream>>>(Qw, Kw, Vw, mbits, Op0, Op1, Lp);
  attn_reduce_kernel<<<8192, 256, 0, stream>>>(Op0, Op1, Lp);
}

// Round 19
// 201.473 us; speedup vs baseline: 1.1262x; 1.1262x over previous
//
#include <hip/hip_runtime.h>
#include <type_traits>

typedef __bf16 bf16_t;
typedef __attribute__((ext_vector_type(8))) __bf16 bf16x8;
typedef __attribute__((ext_vector_type(4))) float f32x4;
typedef __attribute__((ext_vector_type(16))) float f32x16;

__device__ __forceinline__ void async16(const void* g, void* lds) {
  __builtin_amdgcn_global_load_lds((const __attribute__((address_space(1))) unsigned int*)g,
                                   (__attribute__((address_space(3))) unsigned int*)lds, 16, 0, 0);
}

__device__ __forceinline__ unsigned pk2(float lo, float hi) {
  unsigned short a = __builtin_bit_cast(unsigned short, (__bf16)lo);
  unsigned short b = __builtin_bit_cast(unsigned short, (__bf16)hi);
  return (unsigned)a | ((unsigned)b << 16);
}

// exchange register halves across lane<32 / lane>=32 (VALU pipe, not LDS)
__device__ __forceinline__ void plswap(unsigned& a, unsigned& b) {
#if __has_builtin(__builtin_amdgcn_permlane32_swap)
  auto r = __builtin_amdgcn_permlane32_swap((int)a, (int)b, false, false);
  a = (unsigned)r[0];
  b = (unsigned)r[1];
#else
  const bool hb = (threadIdx.x & 32) != 0;
  unsigned bx = (unsigned)__shfl_xor((int)b, 32);
  unsigned ax = (unsigned)__shfl_xor((int)a, 32);
  unsigned na = hb ? bx : a;
  unsigned nb = hb ? b : ax;
  a = na; b = nb;
#endif
}

// ---------------- merged prep: pack_mask | wt transpose-cvt | from-cvt | to-cvt ----------------
__global__ __launch_bounds__(256) void prep_kernel(const int* __restrict__ mask, unsigned long long* __restrict__ mb,
                                                   const float* __restrict__ Wq, const float* __restrict__ Wk,
                                                   const float* __restrict__ Wv, bf16_t* __restrict__ Wt,
                                                   const float* __restrict__ from, bf16_t* __restrict__ inbF,
                                                   const float* __restrict__ to_, bf16_t* __restrict__ inbT) {
  const int bid = blockIdx.x, tid = threadIdx.x;
  if (bid < 2048) {
    const int lane = tid & 63, w = tid >> 6;
    for (int i = 0; i < 32; ++i) {
      size_t word = (size_t)bid * 128 + (size_t)i * 4 + w;
      unsigned long long bits = __ballot(mask[word * 64 + lane] != 0);
      if (lane == 0) mb[word] = bits;
    }
  } else if (bid < 3584) {
    const int idx = bid - 2048;
    const int z = idx >> 9, r = idx & 511;
    const float* src = (z == 0) ? Wq : ((z == 1) ? Wk : Wv);
    const float sc = (z == 0) ? 0.18033688011112042f : 1.0f;  // (1/8)*log2(e)
    bf16_t* dst = Wt + (size_t)z * 1024 * 1024;
    const int n = (r & 15) * 64 + (tid & 63);
    const int k8 = (r >> 4) * 4 + (tid >> 6);
    bf16x8 o;
#pragma unroll
    for (int j = 0; j < 8; ++j) o[j] = (__bf16)(src[(size_t)(k8 * 8 + j) * 1024 + n] * sc);
    *(bf16x8*)(dst + (size_t)n * 1024 + k8 * 8) = o;
  } else {
    const bool isF = bid < 7680;
    const size_t i = (size_t)(bid - (isF ? 3584 : 7680)) * 256 + tid;
    const float4* in4 = (const float4*)(isF ? from : to_);
    bf16_t* outp = isF ? inbF : inbT;
    float4 a = in4[i * 2], b = in4[i * 2 + 1];
    bf16x8 o;
    o[0] = (__bf16)a.x; o[1] = (__bf16)a.y; o[2] = (__bf16)a.z; o[3] = (__bf16)a.w;
    o[4] = (__bf16)b.x; o[5] = (__bf16)b.y; o[6] = (__bf16)b.z; o[7] = (__bf16)b.w;
    *(bf16x8*)(outp + i * 8) = o;
  }
}

// ---------------- merged projection GEMM (double-buffered BK=32), z = blockIdx.z ----------------
__global__ __launch_bounds__(256) void proj_kernel(const bf16_t* __restrict__ inbF, const bf16_t* __restrict__ inbT,
                                                   const bf16_t* __restrict__ Wt,
                                                   const float* __restrict__ bq, const float* __restrict__ bk,
                                                   const float* __restrict__ bv,
                                                   bf16_t* __restrict__ Qw, bf16_t* __restrict__ Kw,
                                                   bf16_t* __restrict__ Vw) {
  __shared__ __align__(16) unsigned char smem[33792];
  bf16_t* se = (bf16_t*)smem;
  const int z = blockIdx.z;
  const bf16_t* A = (z == 0) ? inbF : inbT;
  const bf16_t* Wz = Wt + (size_t)z * 1024 * 1024;
  const float* bias = (z == 0) ? bq : ((z == 1) ? bk : bv);
  bf16_t* dst = (z == 0) ? Qw : ((z == 1) ? Kw : Vw);
  const float bscale = (z == 0) ? 0.18033688011112042f : 1.0f;

  const int tid = threadIdx.x, lane = tid & 63, w = tid >> 6;
  const int m0 = blockIdx.x * 128, n0 = blockIdx.y * 128;
  const int wm = (w >> 1) * 64, wn = (w & 1) * 64;
  const int r = lane & 15, kq = lane >> 4;
  const int srow = lane >> 2, sslot = lane & 3;
  f32x4 acc[4][4] = {};

  auto stage = [&](int buf, int k0) {
    bf16_t* Ad = se + buf * 4096;
    bf16_t* Bd = se + 8192 + buf * 4096;
#pragma unroll
    for (int it = 0; it < 2; ++it) {
      const int c = it * 4 + w;
      const int row = c * 16 + srow;
      async16(A + (size_t)(m0 + row) * 1024 + k0 + ((sslot ^ (row & 3)) * 8), Ad + c * 512);
      async16(Wz + (size_t)(n0 + row) * 1024 + k0 + ((sslot ^ (row & 3)) * 8), Bd + c * 512);
    }
  };

  stage(0, 0);
  __syncthreads();
  for (int tile = 0; tile < 32; ++tile) {
    const int cur = tile & 1;
    if (tile < 31) stage(cur ^ 1, (tile + 1) * 32);
    const bf16_t* Al = se + cur * 4096;
    const bf16_t* Bl = se + 8192 + cur * 4096;
    bf16x8 af[4], bfr[4];
#pragma unroll
    for (int i = 0; i < 4; ++i) {
      const int ra = wm + i * 16 + r;
      af[i] = *(const bf16x8*)(Al + ra * 32 + ((kq ^ (ra & 3)) * 8));
      const int rb = wn + i * 16 + r;
      bfr[i] = *(const bf16x8*)(Bl + rb * 32 + ((kq ^ (rb & 3)) * 8));
    }
    __builtin_amdgcn_s_setprio(1);
#pragma unroll
    for (int i = 0; i < 4; ++i)
#pragma unroll
      for (int j = 0; j < 4; ++j)
        acc[i][j] = __builtin_amdgcn_mfma_f32_16x16x32_bf16(af[i], bfr[j], acc[i][j], 0, 0, 0);
    __builtin_amdgcn_s_setprio(0);
    __syncthreads();
  }

  bf16_t* Cl = se;
  float bvv[4];
#pragma unroll
  for (int j = 0; j < 4; ++j) bvv[j] = bias[n0 + wn + j * 16 + r] * bscale;
#pragma unroll
  for (int i = 0; i < 4; ++i)
#pragma unroll
    for (int j = 0; j < 4; ++j)
#pragma unroll
      for (int g = 0; g < 4; ++g)
        Cl[(wm + i * 16 + kq * 4 + g) * 132 + wn + j * 16 + r] = (__bf16)(acc[i][j][g] + bvv[j]);
  __syncthreads();

  const int b = m0 >> 11, sbase = m0 & 2047;
  if (z == 0) {
#pragma unroll
    for (int q = 0; q < 8; ++q) {
      const int cid = q * 256 + tid;
      const int m = cid >> 4, c = (cid >> 3) & 1, d8 = cid & 7;
      bf16x8 val = *(const bf16x8*)(Cl + m * 132 + c * 64 + d8 * 8);
      *(bf16x8*)(dst + ((size_t)(b * 16 + (n0 >> 6) + c) * 2048 + sbase + m) * 64 + d8 * 8) = val;
    }
  } else if (z == 1) {
#pragma unroll
    for (int q = 0; q < 8; ++q) {
      const int cid = q * 256 + tid;
      const int hh = cid >> 7, m = cid & 127;
      bf16x8 val;
#pragma unroll
      for (int dd = 0; dd < 8; ++dd) val[dd] = Cl[m * 132 + dd * 16 + hh];
      *(bf16x8*)(dst + ((size_t)(b * 16 + hh) * 2048 + sbase + m) * 64 + (n0 >> 4)) = val;
    }
  } else {
#pragma unroll
    for (int q = 0; q < 8; ++q) {
      const int cid = q * 256 + tid;
      const int nl = cid >> 4, m8 = cid & 15;
      bf16x8 val;
#pragma unroll
      for (int s = 0; s < 8; ++s) val[s] = Cl[(m8 * 8 + s) * 132 + nl];
      const int hh = (n0 >> 6) + (nl >> 6), dd = nl & 63;
      *(bf16x8*)(dst + ((size_t)(b * 16 + hh) * 64 + dd) * 2048 + sbase + m8 * 8) = val;
    }
  }
}

// ---------------- flash attention: R16 structure + nibble-LUT mask C-init (LUT past staging) ----------------
// grid 512 (2/CU), 4 waves x 64 f, XCD-local (b,h) remap, T-tiles 64, dbuf K/V (staging 32KB:
// K0=[0,8K) K1=[8K,16K) V0=[16K,24K) V1=[24K,32K)); LUT at byte 32768 (128B, outside staging —
// R18's collision fixed). C-init via 16-entry LDS nibble-LUT: LUT[nib] = 4 packed bf16
// (bit?0:-29952); ds_read_b64 + 1-op/elem unpack replaces the 3-op/elem shift chain.
// S^T = mfma32(K,Q): C col=f=lane&31, row=t=(reg&3)+8*(reg>>2)+4*hi. alpha*log2e folded into Wq/bq.
__global__ __launch_bounds__(256, 2) void attn_kernel(const bf16_t* __restrict__ Q, const bf16_t* __restrict__ K,
                                                      const bf16_t* __restrict__ VT,
                                                      const unsigned long long* __restrict__ mb,
                                                      float* __restrict__ out) {
  __shared__ __align__(16) unsigned char smem[33024];  // 32KB staging + 128B LUT + pad
  bf16_t* se = (bf16_t*)smem;
  const int tid = threadIdx.x, lane = tid & 63, w = tid >> 6;
  const int cl = lane & 31, hi = lane >> 5;

  // XCD-locality remap: lid&7 = XCD; each XCD serves 8 whole (b,h) pairs (K/V L2-resident).
  const int lid = blockIdx.x + 8 * (blockIdx.y + 16 * blockIdx.z);
  const int xcd = lid & 7, q_ = lid >> 3;
  const int pairIdx = xcd * 8 + (q_ & 7);
  const int f0 = (q_ >> 3) * 256;
  const int h = pairIdx & 15, b = pairIdx >> 4;

  const size_t bh = (size_t)b * 16 + h;
  const int fw = f0 + w * 64;

  // nibble LUT at byte 32768 (beyond staging): LUT[nib] halfword j = (nib>>j)&1 ? 0 : 0xC6EA
  unsigned long long* lut = (unsigned long long*)(smem + 32768);
  if (tid < 16) {
    unsigned long long v = 0;
#pragma unroll
    for (int j = 0; j < 4; ++j)
      if (!((tid >> j) & 1)) v |= 0xC6EAull << (16 * j);
    lut[tid] = v;
  }
  const uint2* lut2 = (const uint2*)lut;

  // Q B-frags: qf[fb][ks] = Q[fw + fb*32 + cl][ks*16 + hi*8 + j]
  const bf16_t* Qb = Q + (bh * 2048 + fw) * 64;
  bf16x8 qf[2][4];
#pragma unroll
  for (int fb = 0; fb < 2; ++fb)
#pragma unroll
    for (int ks = 0; ks < 4; ++ks)
      qf[fb][ks] = *(const bf16x8*)(Qb + (fb * 32 + cl) * 64 + ks * 16 + hi * 8);

  f32x16 Of[2][2] = {};     // [fb][db]: O[row=f][col=d], col = db*32+cl
  float lacc[2] = {0.f, 0.f};
  bf16x8 paw[2][4];         // [fb][kt] PV A-frags (P in bf16), rebuilt each tile AFTER PV consumes

  const unsigned long long* mrow[2];
  mrow[0] = mb + ((size_t)b * 2048 + fw + cl) * 32;
  mrow[1] = mb + ((size_t)b * 2048 + fw + 32 + cl) * 32;

  // hoisted per-thread staging bases (pre-swizzled global source, linear LDS dest)
  const int row8 = lane >> 3, slot = lane & 7;
  const int swz = (slot ^ row8) * 8;
  const bf16_t* kgb[2];
  const bf16_t* vgb[2];
#pragma unroll
  for (int it = 0; it < 2; ++it) {
    const int row = it * 32 + w * 8 + row8;
    kgb[it] = K + (bh * 2048 + row) * 64 + swz;
    vgb[it] = VT + (bh * 64 + row) * 2048 + swz;
  }

  auto stage_k = [&](int buf, int tile) {
    bf16_t* kd = se + buf * 4096 + w * 512;
#pragma unroll
    for (int it = 0; it < 2; ++it)
      async16(kgb[it] + (size_t)tile * 4096, kd + it * 2048);
  };
  auto stage_v = [&](int buf, int tile) {
    bf16_t* vd = se + 8192 + buf * 4096 + w * 512;
#pragma unroll
    for (int it = 0; it < 2; ++it)
      async16(vgb[it] + (size_t)tile * 64, vd + it * 2048);
  };

  // PV: O[f][d] += P[f][t] * V[t][d], using paw (prev tile) and Vbuf[vbuf]
  auto pv_step = [&](int vbuf) {
    const bf16_t* Vl = se + 8192 + vbuf * 4096;
    __builtin_amdgcn_s_setprio(1);
#pragma unroll
    for (int db = 0; db < 2; ++db) {
      const int vrow0 = db * 32 + cl;
#pragma unroll
      for (int kt = 0; kt < 4; ++kt) {
        bf16x8 vf = *(const bf16x8*)(Vl + vrow0 * 64 + (((2 * kt + hi) ^ (vrow0 & 7)) * 8));
        Of[0][db] = __builtin_amdgcn_mfma_f32_32x32x16_bf16(paw[0][kt], vf, Of[0][db], 0, 0, 0);
        Of[1][db] = __builtin_amdgcn_mfma_f32_32x32x16_bf16(paw[1][kt], vf, Of[1][db], 0, 0, 0);
      }
    }
    __builtin_amdgcn_s_setprio(0);
  };

  unsigned long long mA[2], mB[2];
  stage_k(0, 0);
  mA[0] = mrow[0][0];
  mA[1] = mrow[1][0];
  __syncthreads();   // covers staging AND the LUT writes

  auto body = [&](auto curc, auto dopvc, unsigned long long (&mc)[2], unsigned long long (&mn)[2], int tile) {
    constexpr int cur = decltype(curc)::value;
    constexpr bool dopv = decltype(dopvc)::value;
    if (tile < 31) {
      stage_k(cur ^ 1, tile + 1);
      mn[0] = mrow[0][tile + 1];
      mn[1] = mrow[1][tile + 1];
    }
    stage_v(cur, tile);
    const bf16_t* Kl = se + cur * 4096;

    // C-init from mask nibbles via LDS LUT: st = bit ? 0 : -29952 (exp2 underflow -> exact 0)
    f32x16 st0[2], st1[2];
#pragma unroll
    for (int fb = 0; fb < 2; ++fb) {
      const unsigned mw0 = (unsigned)(mc[fb] >> (4 * hi));
      const unsigned mw1 = (unsigned)(mc[fb] >> (32 + 4 * hi));
#pragma unroll
      for (int q = 0; q < 4; ++q) {
        const uint2 e0 = lut2[(mw0 >> (8 * q)) & 15u];
        const uint2 e1 = lut2[(mw1 >> (8 * q)) & 15u];
        st0[fb][q * 4 + 0] = __uint_as_float(e0.x << 16);
        st0[fb][q * 4 + 1] = __uint_as_float(e0.x & 0xFFFF0000u);
        st0[fb][q * 4 + 2] = __uint_as_float(e0.y << 16);
        st0[fb][q * 4 + 3] = __uint_as_float(e0.y & 0xFFFF0000u);
        st1[fb][q * 4 + 0] = __uint_as_float(e1.x << 16);
        st1[fb][q * 4 + 1] = __uint_as_float(e1.x & 0xFFFF0000u);
        st1[fb][q * 4 + 2] = __uint_as_float(e1.y << 16);
        st1[fb][q * 4 + 3] = __uint_as_float(e1.y & 0xFFFF0000u);
      }
    }

    // QK ts=0
    {
      const int krow = cl;
      __builtin_amdgcn_s_setprio(1);
#pragma unroll
      for (int ks = 0; ks < 4; ++ks) {
        bf16x8 kf = *(const bf16x8*)(Kl + krow * 64 + (((2 * ks + hi) ^ (krow & 7)) * 8));
        st0[0] = __builtin_amdgcn_mfma_f32_32x32x16_bf16(kf, qf[0][ks], st0[0], 0, 0, 0);
        st0[1] = __builtin_amdgcn_mfma_f32_32x32x16_bf16(kf, qf[1][ks], st0[1], 0, 0, 0);
      }
      __builtin_amdgcn_s_setprio(0);
    }

    // PV of previous tile (independent of this tile's softmax; overlaps with it)
    if constexpr (dopv) pv_step(cur ^ 1);

    // QK ts=1
    {
      const int krow = 32 + cl;
      __builtin_amdgcn_s_setprio(1);
#pragma unroll
      for (int ks = 0; ks < 4; ++ks) {
        bf16x8 kf = *(const bf16x8*)(Kl + krow * 64 + (((2 * ks + hi) ^ (krow & 7)) * 8));
        st1[0] = __builtin_amdgcn_mfma_f32_32x32x16_bf16(kf, qf[0][ks], st1[0], 0, 0, 0);
        st1[1] = __builtin_amdgcn_mfma_f32_32x32x16_bf16(kf, qf[1][ks], st1[1], 0, 0, 0);
      }
      __builtin_amdgcn_s_setprio(0);
    }

    // softmax: p = exp2(st) (masked underflow to 0) -> lacc -> pack -> swap -> paw
#pragma unroll
    for (int ts = 0; ts < 2; ++ts) {
#pragma unroll
      for (int fb = 0; fb < 2; ++fb) {
        const f32x16& stf = (ts == 0) ? st0[fb] : st1[fb];
        float pv[16];
#pragma unroll
        for (int q = 0; q < 4; ++q)
#pragma unroll
          for (int e = 0; e < 4; ++e) {
            const int idx = q * 4 + e;
            float p = __builtin_amdgcn_exp2f(stf[idx]);
            lacc[fb] += p;
            pv[idx] = p;
          }
#pragma unroll
        for (int kl = 0; kl < 2; ++kl) {
          const int qa = 2 * kl, qb = qa + 1;
          unsigned x0 = pk2(pv[qa * 4 + 0], pv[qa * 4 + 1]);
          unsigned y0 = pk2(pv[qb * 4 + 0], pv[qb * 4 + 1]);
          unsigned x1 = pk2(pv[qa * 4 + 2], pv[qa * 4 + 3]);
          unsigned y1 = pk2(pv[qb * 4 + 2], pv[qb * 4 + 3]);
          plswap(x0, y0);
          plswap(x1, y1);
          union { unsigned u[4]; bf16x8 v; } tmp;
          tmp.u[0] = x0; tmp.u[1] = x1; tmp.u[2] = y0; tmp.u[3] = y1;
          paw[fb][ts * 2 + kl] = tmp.v;
        }
      }
    }
    __syncthreads();
  };

  using c0 = std::integral_constant<int, 0>;
  using c1 = std::integral_constant<int, 1>;
  using bF = std::integral_constant<bool, false>;
  using bT = std::integral_constant<bool, true>;

  body(c0{}, bF{}, mA, mB, 0);
  body(c1{}, bT{}, mB, mA, 1);
  for (int tile = 2; tile < 32; tile += 2) {
    body(c0{}, bT{}, mA, mB, tile);
    body(c1{}, bT{}, mB, mA, tile + 1);
  }
  pv_step(1);  // PV of tile 31 (Vbuf[31&1]=1)

  // ---- epilogue: cross-half l reduce, redistribute per C-row via wave-local LDS, scale, store ----
#pragma unroll
  for (int fb = 0; fb < 2; ++fb) lacc[fb] += __shfl_xor(lacc[fb], 32);
  float* lsh = (float*)smem;  // [4 waves][64 f]; wave-local (Kbuf region, no longer read)
  if (hi == 0) {
    lsh[w * 64 + cl] = lacc[0];
    lsh[w * 64 + 32 + cl] = lacc[1];
  }
#pragma unroll
  for (int fb = 0; fb < 2; ++fb)
#pragma unroll
    for (int q = 0; q < 4; ++q)
#pragma unroll
      for (int e = 0; e < 4; ++e) {
        const int idx = q * 4 + e;
        const int row = e + 8 * q + 4 * hi;
        const float li = 1.0f / lsh[w * 64 + fb * 32 + row];
        const size_t orow = ((size_t)b * 2048 + fw + fb * 32 + row) * 1024 + h * 64;
        out[orow + cl] = Of[fb][0][idx] * li;
        out[orow + 32 + cl] = Of[fb][1][idx] * li;
      }
}

extern "C" void kernel_launch(void* const* d_in, const int* in_sizes, int n_in,
                              void* d_out, int out_size, void* d_ws, size_t ws_size,
                              hipStream_t stream) {
  (void)in_sizes; (void)n_in; (void)out_size; (void)ws_size;
  const float* from = (const float*)d_in[0];
  const float* to_  = (const float*)d_in[1];
  const int*   mask = (const int*)d_in[2];
  const float* Wq = (const float*)d_in[3];
  const float* bq = (const float*)d_in[4];
  const float* Wk = (const float*)d_in[5];
  const float* bk = (const float*)d_in[6];
  const float* Wv = (const float*)d_in[7];
  const float* bv = (const float*)d_in[8];
  float* out = (float*)d_out;
  char* ws = (char*)d_ws;

  bf16_t* Qw = (bf16_t*)(ws);                                    // 16 MiB [B,H,F,D]
  bf16_t* Kw = (bf16_t*)(ws + (size_t)(1u << 24));               // 16 MiB [B,H,T,D]
  bf16_t* Vw = (bf16_t*)(ws + (size_t)(2u << 24));               // 16 MiB [B,H,D,T]
  bf16_t* Wt = (bf16_t*)(ws + (size_t)(3u << 24));               // 6 MiB (3x [1024][1024])
  unsigned long long* mbits = (unsigned long long*)(ws + (size_t)(3u << 24) + (size_t)(6u << 20));  // 2 MiB
  bf16_t* inbF = (bf16_t*)(ws + (size_t)(3u << 24) + (size_t)(8u << 20));  // 16 MiB (from, bf16)
  bf16_t* inbT = (bf16_t*)d_out;  // to-tensor bf16 scratch in d_out's first 16 MiB (attn overwrites later)

  prep_kernel<<<11776, 256, 0, stream>>>(mask, mbits, Wq, Wk, Wv, Wt, from, inbF, to_, inbT);
  proj_kernel<<<dim3(64, 8, 3), 256, 0, stream>>>(inbF, inbT, Wt, bq, bk, bv, Qw, Kw, Vw);
  attn_kernel<<<dim3(8, 16, 4), 256, 0, stream>>>(Qw, Kw, Vw, mbits, out);
}